// Round 15
// baseline (220.061 us; speedup 1.0000x reference)
//
#include <hip/hip_runtime.h>
#include <hip/hip_fp16.h>
#include <math.h>

#define NB   16
#define SLA  1024
#define SLB  1024
#define HH   512

typedef __attribute__((ext_vector_type(4))) float  f32x4;
typedef __attribute__((ext_vector_type(8))) short  s16x8;
typedef __attribute__((ext_vector_type(4))) int    i32x4;

#define QS    (6.5f / 127.f)
#define QINVS (127.f / 6.5f)

__device__ __forceinline__ unsigned short f2bf(float x){
  unsigned u = __float_as_uint(x);
  u += 0x7fffu + ((u >> 16) & 1u);
  return (unsigned short)(u >> 16);
}
__device__ __forceinline__ float bf2f(unsigned short h){
  return __uint_as_float(((unsigned)h) << 16);
}
__device__ __forceinline__ float h2f(unsigned short h){
  return __half2float(__ushort_as_half(h));
}
// order-preserving float->uint key (monotone); atomicMax-able
__device__ __forceinline__ unsigned fkey(float f){
  unsigned u = __float_as_uint(f);
  return ((int)u < 0) ? ~u : (u | 0x80000000u);
}
__device__ __forceinline__ float funkey(unsigned k){
  return __uint_as_float((k & 0x80000000u) ? (k & 0x7fffffffu) : ~k);
}

// async global->LDS, 16B per lane. LDS dest must be wave-uniform base + lane*16.
__device__ __forceinline__ void gl2lds16(const void* g, void* l){
  __builtin_amdgcn_global_load_lds(
      (__attribute__((address_space(1))) unsigned int*)(unsigned long long)(size_t)g,
      (__attribute__((address_space(3))) unsigned int*)(unsigned int)(size_t)l,
      16, 0, 0);
}

// ---------------------------------------------------------------------------
// scan: per (batch, mask) compacted index list + counts; also zeroes the
// max-key accumulators for this (b, which).
// ---------------------------------------------------------------------------
__global__ __launch_bounds__(256) void scan_kernel(
    const float* __restrict__ pmask, const float* __restrict__ hmask,
    int* __restrict__ pIdx, int* __restrict__ hIdx,
    int* __restrict__ pCnt, int* __restrict__ hCnt,
    int* __restrict__ pPad, int* __restrict__ hPad,
    unsigned* __restrict__ rowMaxU, unsigned* __restrict__ colMaxU)
{
  __shared__ int ps[256];
  const int b     = blockIdx.x;
  const int which = blockIdx.y;
  const int t     = threadIdx.x;
  const float* m = (which ? hmask : pmask) + b * 1024;
  int* idx = (which ? hIdx : pIdx) + b * 1024;
  int* cnt = which ? hCnt : pCnt;
  int* pad = which ? hPad : pPad;

  // zero accumulators (independent of scan)
  #pragma unroll
  for (int v = 0; v < 4; ++v){
    int g = b * 1024 + t + v * 256;
    if (which == 0){
      rowMaxU[g] = 0u;
    } else {
      colMaxU[g] = 0u;
    }
  }

  int f[4], s = 0;
  #pragma unroll
  for (int e = 0; e < 4; ++e){
    f[e] = m[t * 4 + e] > 0.5f ? 1 : 0;
    s += f[e];
  }
  ps[t] = s;
  __syncthreads();
  for (int off = 1; off < 256; off <<= 1){
    int v = (t >= off) ? ps[t - off] : 0;
    __syncthreads();
    ps[t] += v;
    __syncthreads();
  }
  int pos = ps[t] - s;
  #pragma unroll
  for (int e = 0; e < 4; ++e){
    if (f[e]) idx[pos++] = t * 4 + e;
  }
  if (t == 0){
    int total = ps[255];
    cnt[b] = total;
    pad[b] = (total + 127) & ~127;
  }
}

// ---------------------------------------------------------------------------
// zero_out: zero the masked-out output rows (harness poisons d_out)
// ---------------------------------------------------------------------------
__global__ __launch_bounds__(256) void zero_out_kernel(
    const float* __restrict__ pmask, const float* __restrict__ hmask,
    float* __restrict__ out)
{
  const int r = blockIdx.x * 4 + (threadIdx.x >> 6);   // 0..32767
  const int side = r >> 14;
  const int b    = (r >> 10) & 15;
  const int row  = r & 1023;
  const float mv = (side ? hmask : pmask)[b * 1024 + row];
  if (mv > 0.5f) return;
  float4 z = {0.f, 0.f, 0.f, 0.f};
  float* p = out + (size_t)side * NB * SLA * HH
                 + ((size_t)b * 1024 + row) * 512 + (threadIdx.x & 63) * 8;
  *(float4*)p = z;
  *(float4*)(p + 4) = z;
}

// ---------------------------------------------------------------------------
// cvt_gather: gather masked-in rows -> i8 digit planes (compact) + bf16
// transposed XT [b][512][1024] (zeros in pad fringe). blockIdx.z = b+16*tensor
// ---------------------------------------------------------------------------
__global__ __launch_bounds__(256) void cvt_gather_kernel(
    const float* __restrict__ prem, const float* __restrict__ hyp,
    const int* __restrict__ pIdx, const int* __restrict__ hIdx,
    const int* __restrict__ pCnt, const int* __restrict__ hCnt,
    const int* __restrict__ pPad, const int* __restrict__ hPad,
    char* __restrict__ premD1, char* __restrict__ premD0,
    char* __restrict__ hypD1,  char* __restrict__ hypD0,
    unsigned short* __restrict__ PremT, unsigned short* __restrict__ HypT)
{
  __shared__ unsigned short tv[64][72];
  __shared__ int sIdx[64];

  const int tensor = blockIdx.z >> 4;
  const int b  = blockIdx.z & 15;
  const int l0 = blockIdx.y * 64;
  const int h0 = blockIdx.x * 64;
  const int t  = threadIdx.x;

  const int cnt = tensor ? hCnt[b] : pCnt[b];
  const int pad = tensor ? hPad[b] : pPad[b];
  if (l0 >= pad) return;

  const float* X = tensor ? hyp : prem;
  const int* idx = (tensor ? hIdx : pIdx) + b * 1024;
  char* D1 = tensor ? hypD1 : premD1;
  char* D0 = tensor ? hypD0 : premD0;
  unsigned short* XT = tensor ? HypT : PremT;

  if (t < 64){
    int jc = l0 + t;
    sIdx[t] = (jc < cnt) ? idx[jc] : -1;
  }
  __syncthreads();

  #pragma unroll
  for (int it = 0; it < 4; ++it){
    int r = (t >> 4) + it * 16;
    int c = (t & 15) * 4;
    int orig = sIdx[r];
    float4 x = {0.f, 0.f, 0.f, 0.f};
    if (orig >= 0)
      x = *(const float4*)(X + ((size_t)b * 1024 + orig) * HH + h0 + c);
    float xv[4] = {x.x, x.y, x.z, x.w};
    char d1v[4], d0v[4];
    #pragma unroll
    for (int e = 0; e < 4; ++e){
      float xs = xv[e] * QINVS;
      float x1 = rintf(xs);
      x1 = fminf(127.f, fmaxf(-127.f, x1));
      float x0 = rintf((xs - x1) * 256.f);
      x0 = fminf(127.f, fmaxf(-128.f, x0));
      d1v[e] = (char)(int)x1;
      d0v[e] = (char)(int)x0;
      tv[c + e][r] = f2bf(xv[e]);
    }
    size_t go = ((size_t)b * 1024 + l0 + r) * HH + h0 + c;
    *(char4*)(D1 + go) = make_char4(d1v[0], d1v[1], d1v[2], d1v[3]);
    *(char4*)(D0 + go) = make_char4(d0v[0], d0v[1], d0v[2], d0v[3]);
  }
  __syncthreads();
  const int w   = t >> 2;
  const int seg = (t & 3) * 16;
  const uint4* src = (const uint4*)&tv[w][seg];
  uint4* dst = (uint4*)(XT + ((size_t)b * HH + h0 + w) * 1024 + l0 + seg);
  dst[0] = src[0];
  dst[1] = src[1];
}

// ---------------------------------------------------------------------------
// sim_v6: compacted i8 GEMM -> sim fp16 AND simT fp16 (LDS transpose in
// epilogue, reusing the dead staging buffers). Block 128(M)x64(N), BK=64.
// Fused epilogue: masked row/col max -> atomicMax on uint keys.
// ---------------------------------------------------------------------------
__global__ __launch_bounds__(256, 3) void sim_gemm_v6_kernel(
    const char* __restrict__ premD1, const char* __restrict__ premD0,
    const char* __restrict__ hypD1,  const char* __restrict__ hypD0,
    const int* __restrict__ pCnt, const int* __restrict__ hCnt,
    const int* __restrict__ pPad, const int* __restrict__ hPad,
    unsigned short* __restrict__ simH, unsigned short* __restrict__ simT,
    unsigned* __restrict__ rowMaxU, unsigned* __restrict__ colMaxU)
{
  union __align__(16) Smem {
    struct {
      char A1[128 * 64];
      char A0[128 * 64];
      char B1[64 * 64];
      char B0[64 * 64];
    } g;                             // 24576 B (GEMM staging)
    unsigned short tp[64][136];      // 17408 B (epilogue transpose, +8 pad)
  };
  __shared__ Smem su;
#define sA1 (su.g.A1)
#define sA0 (su.g.A0)
#define sB1 (su.g.B1)
#define sB0 (su.g.B0)

  const int b  = blockIdx.z;
  const int i0 = blockIdx.y * 128;
  const int j0 = blockIdx.x * 64;
  const int t  = threadIdx.x;

  const int pc = pCnt[b], hc = hCnt[b];
  if (i0 >= pPad[b] || j0 >= hPad[b]) return;

  const char* A1 = premD1 + ((size_t)b * 1024 + i0) * HH;
  const char* A0 = premD0 + ((size_t)b * 1024 + i0) * HH;
  const char* B1 = hypD1  + ((size_t)b * 1024 + j0) * HH;
  const char* B0 = hypD0  + ((size_t)b * 1024 + j0) * HH;

  const int sr = t >> 2;
  const int gc = ((t & 3) ^ (sr & 3)) * 16;
  const int lco = (t & 3) * 16;

  const int lane = t & 63;
  const int wr = (t >> 7) & 1;
  const int wc = (t >> 6) & 1;
  const int q  = lane >> 4;
  const int ln = lane & 15;
  const int fo = (q ^ (ln & 3)) * 16;

  i32x4 acc1[4][2], accc[4][2];
  #pragma unroll
  for (int mt = 0; mt < 4; ++mt)
    #pragma unroll
    for (int nt = 0; nt < 2; ++nt){
      acc1[mt][nt] = (i32x4){0, 0, 0, 0};
      accc[mt][nt] = (i32x4){0, 0, 0, 0};
    }

  for (int k0 = 0; k0 < HH; k0 += 64){
    __syncthreads();
    {
      const size_t goA = (size_t)sr * HH + k0 + gc;
      gl2lds16(A1 + goA, &sA1[sr * 64 + lco]);
      gl2lds16(A0 + goA, &sA0[sr * 64 + lco]);
      const size_t goA2 = (size_t)(64 + sr) * HH + k0 + gc;
      gl2lds16(A1 + goA2, &sA1[(64 + sr) * 64 + lco]);
      gl2lds16(A0 + goA2, &sA0[(64 + sr) * 64 + lco]);
      gl2lds16(B1 + goA, &sB1[sr * 64 + lco]);
      gl2lds16(B0 + goA, &sB0[sr * 64 + lco]);
    }
    __syncthreads();

    i32x4 af[4], bf1[2], bf0[2];
    #pragma unroll
    for (int mt = 0; mt < 4; ++mt)
      af[mt] = *(const i32x4*)&sA1[(wr * 64 + mt * 16 + ln) * 64 + fo];
    #pragma unroll
    for (int nt = 0; nt < 2; ++nt)
      bf1[nt] = *(const i32x4*)&sB1[(wc * 32 + nt * 16 + ln) * 64 + fo];
    #pragma unroll
    for (int mt = 0; mt < 4; ++mt)
      #pragma unroll
      for (int nt = 0; nt < 2; ++nt)
        acc1[mt][nt] = __builtin_amdgcn_mfma_i32_16x16x64_i8(af[mt], bf1[nt], acc1[mt][nt], 0, 0, 0);
    #pragma unroll
    for (int nt = 0; nt < 2; ++nt)
      bf0[nt] = *(const i32x4*)&sB0[(wc * 32 + nt * 16 + ln) * 64 + fo];
    #pragma unroll
    for (int mt = 0; mt < 4; ++mt)
      #pragma unroll
      for (int nt = 0; nt < 2; ++nt)
        accc[mt][nt] = __builtin_amdgcn_mfma_i32_16x16x64_i8(af[mt], bf0[nt], accc[mt][nt], 0, 0, 0);
    #pragma unroll
    for (int mt = 0; mt < 4; ++mt)
      af[mt] = *(const i32x4*)&sA0[(wr * 64 + mt * 16 + ln) * 64 + fo];
    #pragma unroll
    for (int mt = 0; mt < 4; ++mt)
      #pragma unroll
      for (int nt = 0; nt < 2; ++nt)
        accc[mt][nt] = __builtin_amdgcn_mfma_i32_16x16x64_i8(af[mt], bf1[nt], accc[mt][nt], 0, 0, 0);
  }

  const float S2 = QS * QS;
  unsigned short* simb = simH + ((size_t)b * SLA + i0) * SLB + j0;

  float rmx[16];
  #pragma unroll
  for (int e = 0; e < 16; ++e) rmx[e] = -1e30f;
  float cmx[2];
  cmx[0] = -1e30f; cmx[1] = -1e30f;

  __syncthreads();   // staging LDS dead; all waves past final frag reads -> tp reuse

  #pragma unroll
  for (int mt = 0; mt < 4; ++mt){
    #pragma unroll
    for (int nt = 0; nt < 2; ++nt){
      int col = wc * 32 + nt * 16 + ln;
      bool colv = (j0 + col) < hc;
      unsigned short hv[4];
      #pragma unroll
      for (int rr = 0; rr < 4; ++rr){
        int row = wr * 64 + mt * 16 + q * 4 + rr;
        float f = S2 * ((float)acc1[mt][nt][rr] + (float)accc[mt][nt][rr] * 0.00390625f);
        unsigned short hb = __half_as_ushort(__float2half(f));
        simb[(size_t)row * SLB + col] = hb;
        hv[rr] = hb;
        rmx[mt * 4 + rr] = fmaxf(rmx[mt * 4 + rr], colv ? f : -1e30f);
        cmx[nt] = fmaxf(cmx[nt], (i0 + row) < pc ? f : -1e30f);
      }
      uint2 w;
      w.x = (unsigned)hv[0] | ((unsigned)hv[1] << 16);
      w.y = (unsigned)hv[2] | ((unsigned)hv[3] << 16);
      *(uint2*)&su.tp[col][wr * 64 + mt * 16 + q * 4] = w;
    }
  }
  __syncthreads();
  {
    const int jr  = t >> 2;
    const int seg = (t & 3) * 32;
    const uint4* src = (const uint4*)&su.tp[jr][seg];
    uint4* dst = (uint4*)(simT + ((size_t)b * SLB + j0 + jr) * SLA + i0 + seg);
    dst[0] = src[0];
    dst[1] = src[1];
    dst[2] = src[2];
    dst[3] = src[3];
  }

  #pragma unroll
  for (int e = 0; e < 16; ++e){
    float v = rmx[e];
    v = fmaxf(v, __shfl_xor(v, 1));
    v = fmaxf(v, __shfl_xor(v, 2));
    v = fmaxf(v, __shfl_xor(v, 4));
    v = fmaxf(v, __shfl_xor(v, 8));
    if (ln == 0){
      int row = wr * 64 + (e >> 2) * 16 + q * 4 + (e & 3);
      if (i0 + row < pc)
        atomicMax(rowMaxU + b * 1024 + i0 + row, fkey(v));
    }
  }
  #pragma unroll
  for (int nt = 0; nt < 2; ++nt){
    float v = cmx[nt];
    v = fmaxf(v, __shfl_xor(v, 16));
    v = fmaxf(v, __shfl_xor(v, 32));
    if (q == 0){
      int col = wc * 32 + nt * 16 + ln;
      if (j0 + col < hc)
        atomicMax(colMaxU + b * 1024 + j0 + col, fkey(v));
    }
  }
#undef sA1
#undef sA0
#undef sB1
#undef sB0
}

// ---------------------------------------------------------------------------
// av5: single-barrier double-buffered value GEMM (T3 minimum-2-phase recipe).
// av3/av4's 2-barrier k-loop put the stage latency naked on the critical path
// (the second __syncthreads drains vmcnt(0) right after issue); av4's
// cross-barrier prefetch was drained by the same barrier (Common-mistake #5)
// and regressed. Now: ONE barrier per iter — issue B(t+1) gl2lds + A(t+1)
// register loads, MFMA on buf[cur] (covers both latencies), exp/pack A(t+1)
// into buf[nxt], barrier (loads have aged through MFMA+exp => short drain).
// rowMax read per-thread from global (sRM staging dropped).
// ---------------------------------------------------------------------------
__global__ __launch_bounds__(256, 2) void av5_kernel(
    const unsigned short* __restrict__ simH,
    const unsigned short* __restrict__ simT,
    const unsigned short* __restrict__ HypT, const unsigned short* __restrict__ PremT,
    const unsigned* __restrict__ rowMaxU, const unsigned* __restrict__ colMaxU,
    const int* __restrict__ pIdx, const int* __restrict__ hIdx,
    const int* __restrict__ pCnt, const int* __restrict__ hCnt,
    const int* __restrict__ pPad, const int* __restrict__ hPad,
    float* __restrict__ out)
{
  __shared__ unsigned short sA[2][128 * 64];   // 32 KB
  __shared__ unsigned short sB[2][128 * 64];   // 32 KB
  __shared__ float sScale[128];  // 1/sum
  __shared__ int   sIdx[128];

  const int side = blockIdx.z >> 4;
  const int b    = blockIdx.z & 15;
  const int m0   = blockIdx.y * 128;
  const int n0   = blockIdx.x * 128;
  const int t    = threadIdx.x;

  const int cnt  = side ? hCnt[b] : pCnt[b];
  const int mpad = side ? hPad[b] : pPad[b];
  const int kpad = side ? pPad[b] : hPad[b];
  const int kcnt = side ? pCnt[b] : hCnt[b];
  if (m0 >= mpad) return;

  const int* idx = (side ? hIdx : pIdx) + b * 1024;
  float* o = out + (size_t)side * NB * SLA * HH + (size_t)b * 1024 * 512;

  if (t < 128) sIdx[t] = idx[m0 + t];

  // B staging pattern (gl2lds)
  const int wv = t >> 6;
  const int L  = t & 63;
  const int lr = L >> 3;
  const int sw = L & 7;
  const int gkc = (sw ^ lr) * 8;

  // A staging pattern (exp path)
  const int ar  = t >> 1;          // 0..127 m-row
  const int akh = (t & 1) * 32;    // k half (elements)

  // frag pattern
  const int lane = t & 63;
  const int wr = (t >> 7) & 1;
  const int wc = (t >> 6) & 1;
  const int q  = lane >> 4;
  const int ln = lane & 15;
  const int fsw = ln & 7;

  const unsigned short* As = (side ? simT : simH) + (size_t)b * 1024 * 1024;
  const unsigned short* Bt = (side ? PremT : HypT) + (size_t)b * 512 * 1024;
  const unsigned short* Arow = As + (size_t)(m0 + ar) * 1024 + akh;

  // per-thread row max, direct from global (no LDS staging / barrier dep)
  const float rm = funkey((side ? colMaxU : rowMaxU)[b * 1024 + m0 + ar]);

  float rs = 0.f;

  // --- helpers as lambdas (inlined) ---
  auto stageB = [&](int ic, int buf){
    const int k0 = ic * 64;
    #pragma unroll
    for (int s = 0; s < 4; ++s){
      int row = wv * 32 + s * 8 + lr;
      gl2lds16(Bt + (size_t)(n0 + row) * 1024 + k0 + gkc, &sB[buf][row * 64 + sw * 8]);
    }
  };
  auto expPack = [&](int ic, int buf, uint4 u0, uint4 u1, uint4 u2, uint4 u3){
    const int k0 = ic * 64;
    uint4 ua[4] = {u0, u1, u2, u3};
    const bool full = (k0 + 64 <= kcnt);   // block-uniform branch
    #pragma unroll
    for (int cc = 0; cc < 4; ++cc){
      uint4 u = ua[cc];
      unsigned uw[4] = {u.x, u.y, u.z, u.w};
      unsigned short pb[8];
      if (full){
        #pragma unroll
        for (int d = 0; d < 4; ++d){
          float v0 = h2f((unsigned short)(uw[d] & 0xffff));
          float v1 = h2f((unsigned short)(uw[d] >> 16));
          float p0 = __expf(v0 - rm);
          float p1 = __expf(v1 - rm);
          rs += p0 + p1;
          pb[d * 2]     = f2bf(p0);
          pb[d * 2 + 1] = f2bf(p1);
        }
      } else {
        int kb = k0 + akh + cc * 8;
        #pragma unroll
        for (int d = 0; d < 4; ++d){
          float v0 = h2f((unsigned short)(uw[d] & 0xffff));
          float v1 = h2f((unsigned short)(uw[d] >> 16));
          float p0 = (kb + d * 2 + 0) < kcnt ? __expf(v0 - rm) : 0.f;
          float p1 = (kb + d * 2 + 1) < kcnt ? __expf(v1 - rm) : 0.f;
          rs += p0 + p1;
          pb[d * 2]     = f2bf(p0);
          pb[d * 2 + 1] = f2bf(p1);
        }
      }
      uint4 w;
      w.x = (unsigned)pb[0] | ((unsigned)pb[1] << 16);
      w.y = (unsigned)pb[2] | ((unsigned)pb[3] << 16);
      w.z = (unsigned)pb[4] | ((unsigned)pb[5] << 16);
      w.w = (unsigned)pb[6] | ((unsigned)pb[7] << 16);
      int c   = (t & 1) * 4 + cc;
      int pos = c ^ (ar & 7);
      *(uint4*)&sA[buf][ar * 64 + pos * 8] = w;
    }
  };

  f32x4 acc[4][4];
  #pragma unroll
  for (int mt = 0; mt < 4; ++mt)
    #pragma unroll
    for (int nt = 0; nt < 4; ++nt)
      acc[mt][nt] = (f32x4){0.f, 0.f, 0.f, 0.f};

  const int nch = kpad >> 6;

  // prologue: buffer 0 = chunk 0
  stageB(0, 0);
  {
    uint4 a0 = *(const uint4*)(Arow + 0);
    uint4 a1 = *(const uint4*)(Arow + 8);
    uint4 a2 = *(const uint4*)(Arow + 16);
    uint4 a3 = *(const uint4*)(Arow + 24);
    expPack(0, 0, a0, a1, a2, a3);
  }
  __syncthreads();   // sB[0] staged, sA[0] written, sIdx visible

  int cur = 0;
  for (int ic = 0; ic < nch; ++ic){
    const int nxtc = ic + 1;
    const int nxt  = cur ^ 1;
    uint4 a0, a1, a2, a3;
    if (nxtc < nch){
      stageB(nxtc, nxt);                       // B(t+1) in flight across MFMA
      const unsigned short* sp = Arow + nxtc * 64;
      a0 = *(const uint4*)(sp + 0);            // A(t+1) regs in flight across MFMA
      a1 = *(const uint4*)(sp + 8);
      a2 = *(const uint4*)(sp + 16);
      a3 = *(const uint4*)(sp + 24);
    }

    // MFMA on buf[cur] (data visible since last barrier)
    #pragma unroll
    for (int h = 0; h < 2; ++h){
      s16x8 af[4], bfr[4];
      #pragma unroll
      for (int mt = 0; mt < 4; ++mt){
        int r = wr * 64 + mt * 16 + ln;
        af[mt] = *(const s16x8*)&sA[cur][r * 64 + (((h << 2) + q) ^ fsw) * 8];
      }
      #pragma unroll
      for (int nt = 0; nt < 4; ++nt){
        int r = wc * 64 + nt * 16 + ln;
        bfr[nt] = *(const s16x8*)&sB[cur][r * 64 + (((h << 2) + q) ^ fsw) * 8];
      }
      #pragma unroll
      for (int mt = 0; mt < 4; ++mt)
        #pragma unroll
        for (int nt = 0; nt < 4; ++nt)
          acc[mt][nt] = __builtin_amdgcn_mfma_f32_16x16x32_bf16(af[mt], bfr[nt], acc[mt][nt], 0, 0, 0);
    }

    if (nxtc < nch)
      expPack(nxtc, nxt, a0, a1, a2, a3);      // A regs drained here (post-MFMA)

    __syncthreads();   // single barrier: publishes buf[nxt], retires buf[cur] reads
    cur = nxt;
  }

  rs += __shfl_xor(rs, 1);          // combine the two k-halves of row ar
  if ((t & 1) == 0) sScale[ar] = 1.f / rs;
  __syncthreads();

  #pragma unroll
  for (int mt = 0; mt < 4; ++mt)
    #pragma unroll
    for (int nt = 0; nt < 4; ++nt){
      int col = n0 + wc * 64 + nt * 16 + ln;
      #pragma unroll
      for (int rr = 0; rr < 4; ++rr){
        int rowL = wr * 64 + mt * 16 + q * 4 + rr;
        if (m0 + rowL < cnt)
          o[(size_t)sIdx[rowL] * 512 + col] = acc[mt][nt][rr] * sScale[rowL];
      }
    }
}

// ---------------------------------------------------------------------------
extern "C" void kernel_launch(void* const* d_in, const int* in_sizes, int n_in,
                              void* d_out, int out_size, void* d_ws, size_t ws_size,
                              hipStream_t stream)
{
  const float* prem  = (const float*)d_in[0];
  const float* pmask = (const float*)d_in[1];
  const float* hyp   = (const float*)d_in[2];
  const float* hmask = (const float*)d_in[3];
  float* out = (float*)d_out;

  char* ws = (char*)d_ws;
  unsigned short* simH = (unsigned short*)(ws);                // fp16, 32 MB
  unsigned short* simT = (unsigned short*)(ws + 33554432);     // fp16, 32 MB (2nd half of sim reservation)
  unsigned* rowMaxU = (unsigned*)(ws + 67108864);
  unsigned* colMaxU = (unsigned*)(ws + 67108864 + 2 * 65536);
  int* pIdx = (int*)(ws + 67108864 + 4 * 65536);
  int* hIdx = (int*)(ws + 67108864 + 5 * 65536);
  int* pCnt = (int*)(ws + 67108864 + 6 * 65536);
  int* hCnt = (int*)(ws + 67108864 + 6 * 65536 + 256);
  int* pPad = (int*)(ws + 67108864 + 6 * 65536 + 512);
  int* hPad = (int*)(ws + 67108864 + 6 * 65536 + 768);
  const size_t base2 = 67108864 + 4 * 65536 + 1048576;   // 68419584 (layout-stable)
  char* premD1 = (char*)(ws + base2);
  char* premD0 = (char*)(ws + base2 + 8388608);
  char* hypD1  = (char*)(ws + base2 + 16777216);
  char* hypD0  = (char*)(ws + base2 + 25165824);
  unsigned short* PremT = (unsigned short*)(ws + base2 + 33554432);
  unsigned short* HypT  = (unsigned short*)(ws + base2 + 50331648);
  const size_t need = base2 + 100663296;         // 169,082,880 (same as prior rounds)
  if (ws_size < need) return;

  scan_kernel<<<dim3(16, 2), 256, 0, stream>>>(pmask, hmask, pIdx, hIdx,
                                               pCnt, hCnt, pPad, hPad,
                                               rowMaxU, colMaxU);
  zero_out_kernel<<<dim3(8192), 256, 0, stream>>>(pmask, hmask, out);
  cvt_gather_kernel<<<dim3(8, 16, 32), 256, 0, stream>>>(
      prem, hyp, pIdx, hIdx, pCnt, hCnt, pPad, hPad,
      premD1, premD0, hypD1, hypD0, PremT, HypT);
  sim_gemm_v6_kernel<<<dim3(16, 8, NB), 256, 0, stream>>>(
      premD1, premD0, hypD1, hypD0, pCnt, hCnt, pPad, hPad,
      simH, simT, rowMaxU, colMaxU);
  av5_kernel<<<dim3(4, 8, 32), 256, 0, stream>>>(
      simH, simT, HypT, PremT, rowMaxU, colMaxU,
      pIdx, hIdx, pCnt, hCnt, pPad, hPad, out);
}

// Round 18
// 204.995 us; speedup vs baseline: 1.0735x; 1.0735x over previous
//
#include <hip/hip_runtime.h>
#include <hip/hip_fp16.h>
#include <math.h>

#define NB   16
#define SLA  1024
#define SLB  1024
#define HH   512

typedef __attribute__((ext_vector_type(4))) float  f32x4;
typedef __attribute__((ext_vector_type(8))) short  s16x8;
typedef __attribute__((ext_vector_type(4))) int    i32x4;

#define QS    (6.5f / 127.f)
#define QINVS (127.f / 6.5f)

__device__ __forceinline__ unsigned short f2bf(float x){
  unsigned u = __float_as_uint(x);
  u += 0x7fffu + ((u >> 16) & 1u);
  return (unsigned short)(u >> 16);
}
__device__ __forceinline__ float bf2f(unsigned short h){
  return __uint_as_float(((unsigned)h) << 16);
}
__device__ __forceinline__ float h2f(unsigned short h){
  return __half2float(__ushort_as_half(h));
}
// order-preserving float->uint key (monotone); atomicMax-able
__device__ __forceinline__ unsigned fkey(float f){
  unsigned u = __float_as_uint(f);
  return ((int)u < 0) ? ~u : (u | 0x80000000u);
}
__device__ __forceinline__ float funkey(unsigned k){
  return __uint_as_float((k & 0x80000000u) ? (k & 0x7fffffffu) : ~k);
}

// async global->LDS, 16B per lane. LDS dest must be wave-uniform base + lane*16.
__device__ __forceinline__ void gl2lds16(const void* g, void* l){
  __builtin_amdgcn_global_load_lds(
      (__attribute__((address_space(1))) unsigned int*)(unsigned long long)(size_t)g,
      (__attribute__((address_space(3))) unsigned int*)(unsigned int)(size_t)l,
      16, 0, 0);
}

// ---------------------------------------------------------------------------
// scan: per (batch, mask) compacted index list + counts; also zeroes the
// max-key accumulators for this (b, which).
// ---------------------------------------------------------------------------
__global__ __launch_bounds__(256) void scan_kernel(
    const float* __restrict__ pmask, const float* __restrict__ hmask,
    int* __restrict__ pIdx, int* __restrict__ hIdx,
    int* __restrict__ pCnt, int* __restrict__ hCnt,
    int* __restrict__ pPad, int* __restrict__ hPad,
    unsigned* __restrict__ rowMaxU, unsigned* __restrict__ colMaxU)
{
  __shared__ int ps[256];
  const int b     = blockIdx.x;
  const int which = blockIdx.y;
  const int t     = threadIdx.x;
  const float* m = (which ? hmask : pmask) + b * 1024;
  int* idx = (which ? hIdx : pIdx) + b * 1024;
  int* cnt = which ? hCnt : pCnt;
  int* pad = which ? hPad : pPad;

  // zero accumulators (independent of scan)
  #pragma unroll
  for (int v = 0; v < 4; ++v){
    int g = b * 1024 + t + v * 256;
    if (which == 0){
      rowMaxU[g] = 0u;
    } else {
      colMaxU[g] = 0u;
    }
  }

  int f[4], s = 0;
  #pragma unroll
  for (int e = 0; e < 4; ++e){
    f[e] = m[t * 4 + e] > 0.5f ? 1 : 0;
    s += f[e];
  }
  ps[t] = s;
  __syncthreads();
  for (int off = 1; off < 256; off <<= 1){
    int v = (t >= off) ? ps[t - off] : 0;
    __syncthreads();
    ps[t] += v;
    __syncthreads();
  }
  int pos = ps[t] - s;
  #pragma unroll
  for (int e = 0; e < 4; ++e){
    if (f[e]) idx[pos++] = t * 4 + e;
  }
  if (t == 0){
    int total = ps[255];
    cnt[b] = total;
    pad[b] = (total + 127) & ~127;
  }
}

// ---------------------------------------------------------------------------
// zero_out: zero the masked-out output rows (harness poisons d_out)
// ---------------------------------------------------------------------------
__global__ __launch_bounds__(256) void zero_out_kernel(
    const float* __restrict__ pmask, const float* __restrict__ hmask,
    float* __restrict__ out)
{
  const int r = blockIdx.x * 4 + (threadIdx.x >> 6);   // 0..32767
  const int side = r >> 14;
  const int b    = (r >> 10) & 15;
  const int row  = r & 1023;
  const float mv = (side ? hmask : pmask)[b * 1024 + row];
  if (mv > 0.5f) return;
  float4 z = {0.f, 0.f, 0.f, 0.f};
  float* p = out + (size_t)side * NB * SLA * HH
                 + ((size_t)b * 1024 + row) * 512 + (threadIdx.x & 63) * 8;
  *(float4*)p = z;
  *(float4*)(p + 4) = z;
}

// ---------------------------------------------------------------------------
// cvt_gather: gather masked-in rows -> i8 digit planes (compact) + bf16
// transposed XT [b][512][1024] (zeros in pad fringe). blockIdx.z = b+16*tensor
// ---------------------------------------------------------------------------
__global__ __launch_bounds__(256) void cvt_gather_kernel(
    const float* __restrict__ prem, const float* __restrict__ hyp,
    const int* __restrict__ pIdx, const int* __restrict__ hIdx,
    const int* __restrict__ pCnt, const int* __restrict__ hCnt,
    const int* __restrict__ pPad, const int* __restrict__ hPad,
    char* __restrict__ premD1, char* __restrict__ premD0,
    char* __restrict__ hypD1,  char* __restrict__ hypD0,
    unsigned short* __restrict__ PremT, unsigned short* __restrict__ HypT)
{
  __shared__ unsigned short tv[64][72];
  __shared__ int sIdx[64];

  const int tensor = blockIdx.z >> 4;
  const int b  = blockIdx.z & 15;
  const int l0 = blockIdx.y * 64;
  const int h0 = blockIdx.x * 64;
  const int t  = threadIdx.x;

  const int cnt = tensor ? hCnt[b] : pCnt[b];
  const int pad = tensor ? hPad[b] : pPad[b];
  if (l0 >= pad) return;

  const float* X = tensor ? hyp : prem;
  const int* idx = (tensor ? hIdx : pIdx) + b * 1024;
  char* D1 = tensor ? hypD1 : premD1;
  char* D0 = tensor ? hypD0 : premD0;
  unsigned short* XT = tensor ? HypT : PremT;

  if (t < 64){
    int jc = l0 + t;
    sIdx[t] = (jc < cnt) ? idx[jc] : -1;
  }
  __syncthreads();

  #pragma unroll
  for (int it = 0; it < 4; ++it){
    int r = (t >> 4) + it * 16;
    int c = (t & 15) * 4;
    int orig = sIdx[r];
    float4 x = {0.f, 0.f, 0.f, 0.f};
    if (orig >= 0)
      x = *(const float4*)(X + ((size_t)b * 1024 + orig) * HH + h0 + c);
    float xv[4] = {x.x, x.y, x.z, x.w};
    char d1v[4], d0v[4];
    #pragma unroll
    for (int e = 0; e < 4; ++e){
      float xs = xv[e] * QINVS;
      float x1 = rintf(xs);
      x1 = fminf(127.f, fmaxf(-127.f, x1));
      float x0 = rintf((xs - x1) * 256.f);
      x0 = fminf(127.f, fmaxf(-128.f, x0));
      d1v[e] = (char)(int)x1;
      d0v[e] = (char)(int)x0;
      tv[c + e][r] = f2bf(xv[e]);
    }
    size_t go = ((size_t)b * 1024 + l0 + r) * HH + h0 + c;
    *(char4*)(D1 + go) = make_char4(d1v[0], d1v[1], d1v[2], d1v[3]);
    *(char4*)(D0 + go) = make_char4(d0v[0], d0v[1], d0v[2], d0v[3]);
  }
  __syncthreads();
  const int w   = t >> 2;
  const int seg = (t & 3) * 16;
  const uint4* src = (const uint4*)&tv[w][seg];
  uint4* dst = (uint4*)(XT + ((size_t)b * HH + h0 + w) * 1024 + l0 + seg);
  dst[0] = src[0];
  dst[1] = src[1];
}

// ---------------------------------------------------------------------------
// sim_v6: compacted i8 GEMM -> sim fp16 AND simT fp16 (LDS transpose in
// epilogue, reusing the dead staging buffers). Block 128(M)x64(N), BK=64.
// Fused epilogue: masked row/col max -> atomicMax on uint keys.
// ---------------------------------------------------------------------------
__global__ __launch_bounds__(256, 3) void sim_gemm_v6_kernel(
    const char* __restrict__ premD1, const char* __restrict__ premD0,
    const char* __restrict__ hypD1,  const char* __restrict__ hypD0,
    const int* __restrict__ pCnt, const int* __restrict__ hCnt,
    const int* __restrict__ pPad, const int* __restrict__ hPad,
    unsigned short* __restrict__ simH, unsigned short* __restrict__ simT,
    unsigned* __restrict__ rowMaxU, unsigned* __restrict__ colMaxU)
{
  union __align__(16) Smem {
    struct {
      char A1[128 * 64];
      char A0[128 * 64];
      char B1[64 * 64];
      char B0[64 * 64];
    } g;                             // 24576 B (GEMM staging)
    unsigned short tp[64][136];      // 17408 B (epilogue transpose, +8 pad)
  };
  __shared__ Smem su;
#define sA1 (su.g.A1)
#define sA0 (su.g.A0)
#define sB1 (su.g.B1)
#define sB0 (su.g.B0)

  const int b  = blockIdx.z;
  const int i0 = blockIdx.y * 128;
  const int j0 = blockIdx.x * 64;
  const int t  = threadIdx.x;

  const int pc = pCnt[b], hc = hCnt[b];
  if (i0 >= pPad[b] || j0 >= hPad[b]) return;

  const char* A1 = premD1 + ((size_t)b * 1024 + i0) * HH;
  const char* A0 = premD0 + ((size_t)b * 1024 + i0) * HH;
  const char* B1 = hypD1  + ((size_t)b * 1024 + j0) * HH;
  const char* B0 = hypD0  + ((size_t)b * 1024 + j0) * HH;

  const int sr = t >> 2;
  const int gc = ((t & 3) ^ (sr & 3)) * 16;
  const int lco = (t & 3) * 16;

  const int lane = t & 63;
  const int wr = (t >> 7) & 1;
  const int wc = (t >> 6) & 1;
  const int q  = lane >> 4;
  const int ln = lane & 15;
  const int fo = (q ^ (ln & 3)) * 16;

  i32x4 acc1[4][2], accc[4][2];
  #pragma unroll
  for (int mt = 0; mt < 4; ++mt)
    #pragma unroll
    for (int nt = 0; nt < 2; ++nt){
      acc1[mt][nt] = (i32x4){0, 0, 0, 0};
      accc[mt][nt] = (i32x4){0, 0, 0, 0};
    }

  for (int k0 = 0; k0 < HH; k0 += 64){
    __syncthreads();
    {
      const size_t goA = (size_t)sr * HH + k0 + gc;
      gl2lds16(A1 + goA, &sA1[sr * 64 + lco]);
      gl2lds16(A0 + goA, &sA0[sr * 64 + lco]);
      const size_t goA2 = (size_t)(64 + sr) * HH + k0 + gc;
      gl2lds16(A1 + goA2, &sA1[(64 + sr) * 64 + lco]);
      gl2lds16(A0 + goA2, &sA0[(64 + sr) * 64 + lco]);
      gl2lds16(B1 + goA, &sB1[sr * 64 + lco]);
      gl2lds16(B0 + goA, &sB0[sr * 64 + lco]);
    }
    __syncthreads();

    i32x4 af[4], bf1[2], bf0[2];
    #pragma unroll
    for (int mt = 0; mt < 4; ++mt)
      af[mt] = *(const i32x4*)&sA1[(wr * 64 + mt * 16 + ln) * 64 + fo];
    #pragma unroll
    for (int nt = 0; nt < 2; ++nt)
      bf1[nt] = *(const i32x4*)&sB1[(wc * 32 + nt * 16 + ln) * 64 + fo];
    #pragma unroll
    for (int mt = 0; mt < 4; ++mt)
      #pragma unroll
      for (int nt = 0; nt < 2; ++nt)
        acc1[mt][nt] = __builtin_amdgcn_mfma_i32_16x16x64_i8(af[mt], bf1[nt], acc1[mt][nt], 0, 0, 0);
    #pragma unroll
    for (int nt = 0; nt < 2; ++nt)
      bf0[nt] = *(const i32x4*)&sB0[(wc * 32 + nt * 16 + ln) * 64 + fo];
    #pragma unroll
    for (int mt = 0; mt < 4; ++mt)
      #pragma unroll
      for (int nt = 0; nt < 2; ++nt)
        accc[mt][nt] = __builtin_amdgcn_mfma_i32_16x16x64_i8(af[mt], bf0[nt], accc[mt][nt], 0, 0, 0);
    #pragma unroll
    for (int mt = 0; mt < 4; ++mt)
      af[mt] = *(const i32x4*)&sA0[(wr * 64 + mt * 16 + ln) * 64 + fo];
    #pragma unroll
    for (int mt = 0; mt < 4; ++mt)
      #pragma unroll
      for (int nt = 0; nt < 2; ++nt)
        accc[mt][nt] = __builtin_amdgcn_mfma_i32_16x16x64_i8(af[mt], bf1[nt], accc[mt][nt], 0, 0, 0);
  }

  const float S2 = QS * QS;
  unsigned short* simb = simH + ((size_t)b * SLA + i0) * SLB + j0;

  float rmx[16];
  #pragma unroll
  for (int e = 0; e < 16; ++e) rmx[e] = -1e30f;
  float cmx[2];
  cmx[0] = -1e30f; cmx[1] = -1e30f;

  __syncthreads();   // staging LDS dead; all waves past final frag reads -> tp reuse

  #pragma unroll
  for (int mt = 0; mt < 4; ++mt){
    #pragma unroll
    for (int nt = 0; nt < 2; ++nt){
      int col = wc * 32 + nt * 16 + ln;
      bool colv = (j0 + col) < hc;
      unsigned short hv[4];
      #pragma unroll
      for (int rr = 0; rr < 4; ++rr){
        int row = wr * 64 + mt * 16 + q * 4 + rr;
        float f = S2 * ((float)acc1[mt][nt][rr] + (float)accc[mt][nt][rr] * 0.00390625f);
        unsigned short hb = __half_as_ushort(__float2half(f));
        simb[(size_t)row * SLB + col] = hb;
        hv[rr] = hb;
        rmx[mt * 4 + rr] = fmaxf(rmx[mt * 4 + rr], colv ? f : -1e30f);
        cmx[nt] = fmaxf(cmx[nt], (i0 + row) < pc ? f : -1e30f);
      }
      uint2 w;
      w.x = (unsigned)hv[0] | ((unsigned)hv[1] << 16);
      w.y = (unsigned)hv[2] | ((unsigned)hv[3] << 16);
      *(uint2*)&su.tp[col][wr * 64 + mt * 16 + q * 4] = w;
    }
  }
  __syncthreads();
  {
    const int jr  = t >> 2;
    const int seg = (t & 3) * 32;
    const uint4* src = (const uint4*)&su.tp[jr][seg];
    uint4* dst = (uint4*)(simT + ((size_t)b * SLB + j0 + jr) * SLA + i0 + seg);
    dst[0] = src[0];
    dst[1] = src[1];
    dst[2] = src[2];
    dst[3] = src[3];
  }

  #pragma unroll
  for (int e = 0; e < 16; ++e){
    float v = rmx[e];
    v = fmaxf(v, __shfl_xor(v, 1));
    v = fmaxf(v, __shfl_xor(v, 2));
    v = fmaxf(v, __shfl_xor(v, 4));
    v = fmaxf(v, __shfl_xor(v, 8));
    if (ln == 0){
      int row = wr * 64 + (e >> 2) * 16 + q * 4 + (e & 3);
      if (i0 + row < pc)
        atomicMax(rowMaxU + b * 1024 + i0 + row, fkey(v));
    }
  }
  #pragma unroll
  for (int nt = 0; nt < 2; ++nt){
    float v = cmx[nt];
    v = fmaxf(v, __shfl_xor(v, 16));
    v = fmaxf(v, __shfl_xor(v, 32));
    if (q == 0){
      int col = wc * 32 + nt * 16 + ln;
      if (j0 + col < hc)
        atomicMax(colMaxU + b * 1024 + j0 + col, fkey(v));
    }
  }
#undef sA1
#undef sA0
#undef sB1
#undef sB0
}

// ---------------------------------------------------------------------------
// av6: av3's proven 2-barrier structure, M-tile halved 128->64 for occupancy.
// Evidence (R6/R13/R15): perf tracks waves/CU (av3 occ17%=53us, av4 18%=56,
// av5 dbuf occ10%=80); both pipelining attempts regressed (vmcnt(0) drain at
// every barrier — Common-mistake #5; m99/m131 lesson: TLP hides what manual
// pipelining can't). So: 4 waves at 32x64 (acc[2][4], ~half the VGPRs),
// LDS 25KB, live grid ~1024 blocks -> 4 blocks/CU = 16 waves/CU.
// ---------------------------------------------------------------------------
__global__ __launch_bounds__(256, 4) void av6_kernel(
    const unsigned short* __restrict__ simH,
    const unsigned short* __restrict__ simT,
    const unsigned short* __restrict__ HypT, const unsigned short* __restrict__ PremT,
    const unsigned* __restrict__ rowMaxU, const unsigned* __restrict__ colMaxU,
    const int* __restrict__ pIdx, const int* __restrict__ hIdx,
    const int* __restrict__ pCnt, const int* __restrict__ hCnt,
    const int* __restrict__ pPad, const int* __restrict__ hPad,
    float* __restrict__ out)
{
  __shared__ unsigned short sA[64 * 64];    // 8 KB
  __shared__ unsigned short sB[128 * 64];   // 16 KB
  __shared__ float sScale[64];
  __shared__ int   sIdx[64];

  const int side = blockIdx.z >> 4;
  const int b    = blockIdx.z & 15;
  const int m0   = blockIdx.y * 64;
  const int n0   = blockIdx.x * 128;
  const int t    = threadIdx.x;

  const int cnt  = side ? hCnt[b] : pCnt[b];
  const int mpad = side ? hPad[b] : pPad[b];
  const int kpad = side ? pPad[b] : hPad[b];
  const int kcnt = side ? pCnt[b] : hCnt[b];
  if (m0 >= mpad) return;

  const int* idx = (side ? hIdx : pIdx) + b * 1024;
  float* o = out + (size_t)side * NB * SLA * HH + (size_t)b * 1024 * 512;

  if (t < 64) sIdx[t] = idx[m0 + t];

  // B staging pattern (gl2lds): 128 rows x 64 k, 4 waves x 4 issues
  const int wv = t >> 6;
  const int L  = t & 63;
  const int lr = L >> 3;
  const int sw = L & 7;
  const int gkc = (sw ^ lr) * 8;

  // A staging pattern (exp path): 64 rows, 4 threads/row (16 elems each)
  const int ar  = t >> 2;          // 0..63 m-row
  const int akh = (t & 3) * 16;    // k quarter (elements)

  // frag pattern: wave tile 32(M) x 64(N)
  const int lane = t & 63;
  const int wr = (t >> 7) & 1;
  const int wc = (t >> 6) & 1;
  const int q  = lane >> 4;
  const int ln = lane & 15;
  const int fsw = ln & 7;

  const unsigned short* As = (side ? simT : simH) + (size_t)b * 1024 * 1024;
  const unsigned short* Bt = (side ? PremT : HypT) + (size_t)b * 512 * 1024;
  const unsigned short* Arow = As + (size_t)(m0 + ar) * 1024 + akh;

  // per-thread row max, direct from global
  const float rm = funkey((side ? colMaxU : rowMaxU)[b * 1024 + m0 + ar]);

  float rs = 0.f;

  f32x4 acc[2][4];
  #pragma unroll
  for (int mt = 0; mt < 2; ++mt)
    #pragma unroll
    for (int nt = 0; nt < 4; ++nt)
      acc[mt][nt] = (f32x4){0.f, 0.f, 0.f, 0.f};

  for (int k0 = 0; k0 < kpad; k0 += 64){
    __syncthreads();   // prior frag reads done (also covers sIdx first iter)
    // B stage (async, in flight during A exp work)
    #pragma unroll
    for (int s = 0; s < 4; ++s){
      int row = wv * 32 + s * 8 + lr;
      gl2lds16(Bt + (size_t)(n0 + row) * 1024 + k0 + gkc, &sB[row * 64 + sw * 8]);
    }
    // A: read sim fp16 row quarter, exp, accumulate row sum, ds_write swizzled
    {
      const unsigned short* sp = Arow + k0;
      const bool full = (k0 + 64 <= kcnt);   // block-uniform branch
      #pragma unroll
      for (int cc = 0; cc < 2; ++cc){
        uint4 u = *(const uint4*)(sp + cc * 8);
        unsigned uw[4] = {u.x, u.y, u.z, u.w};
        unsigned short pb[8];
        if (full){
          #pragma unroll
          for (int d = 0; d < 4; ++d){
            float v0 = h2f((unsigned short)(uw[d] & 0xffff));
            float v1 = h2f((unsigned short)(uw[d] >> 16));
            float p0 = __expf(v0 - rm);
            float p1 = __expf(v1 - rm);
            rs += p0 + p1;
            pb[d * 2]     = f2bf(p0);
            pb[d * 2 + 1] = f2bf(p1);
          }
        } else {
          int kb = k0 + akh + cc * 8;
          #pragma unroll
          for (int d = 0; d < 4; ++d){
            float v0 = h2f((unsigned short)(uw[d] & 0xffff));
            float v1 = h2f((unsigned short)(uw[d] >> 16));
            float p0 = (kb + d * 2 + 0) < kcnt ? __expf(v0 - rm) : 0.f;
            float p1 = (kb + d * 2 + 1) < kcnt ? __expf(v1 - rm) : 0.f;
            rs += p0 + p1;
            pb[d * 2]     = f2bf(p0);
            pb[d * 2 + 1] = f2bf(p1);
          }
        }
        uint4 w;
        w.x = (unsigned)pb[0] | ((unsigned)pb[1] << 16);
        w.y = (unsigned)pb[2] | ((unsigned)pb[3] << 16);
        w.z = (unsigned)pb[4] | ((unsigned)pb[5] << 16);
        w.w = (unsigned)pb[6] | ((unsigned)pb[7] << 16);
        int c   = (t & 3) * 2 + cc;          // 8-elem group index 0..7
        int pos = c ^ (ar & 7);              // matches read g ^ (row&7)
        *(uint4*)&sA[ar * 64 + pos * 8] = w;
      }
    }
    __syncthreads();

    #pragma unroll
    for (int h = 0; h < 2; ++h){
      s16x8 af[2], bfr[4];
      #pragma unroll
      for (int mt = 0; mt < 2; ++mt){
        int r = wr * 32 + mt * 16 + ln;
        af[mt] = *(const s16x8*)&sA[r * 64 + (((h << 2) + q) ^ fsw) * 8];
      }
      #pragma unroll
      for (int nt = 0; nt < 4; ++nt){
        int r = wc * 64 + nt * 16 + ln;
        bfr[nt] = *(const s16x8*)&sB[r * 64 + (((h << 2) + q) ^ fsw) * 8];
      }
      #pragma unroll
      for (int mt = 0; mt < 2; ++mt)
        #pragma unroll
        for (int nt = 0; nt < 4; ++nt)
          acc[mt][nt] = __builtin_amdgcn_mfma_f32_16x16x32_bf16(af[mt], bfr[nt], acc[mt][nt], 0, 0, 0);
    }
  }

  // combine the 4 k-quarters of row ar (threads t^1, t^2 share ar)
  rs += __shfl_xor(rs, 1);
  rs += __shfl_xor(rs, 2);
  __syncthreads();                  // sA dead; reuse barrier before sScale write
  if ((t & 3) == 0) sScale[ar] = 1.f / rs;
  __syncthreads();

  #pragma unroll
  for (int mt = 0; mt < 2; ++mt)
    #pragma unroll
    for (int nt = 0; nt < 4; ++nt){
      int col = n0 + wc * 64 + nt * 16 + ln;
      #pragma unroll
      for (int rr = 0; rr < 4; ++rr){
        int rowL = wr * 32 + mt * 16 + q * 4 + rr;
        if (m0 + rowL < cnt)
          o[(size_t)sIdx[rowL] * 512 + col] = acc[mt][nt][rr] * sScale[rowL];
      }
    }
}

// ---------------------------------------------------------------------------
extern "C" void kernel_launch(void* const* d_in, const int* in_sizes, int n_in,
                              void* d_out, int out_size, void* d_ws, size_t ws_size,
                              hipStream_t stream)
{
  const float* prem  = (const float*)d_in[0];
  const float* pmask = (const float*)d_in[1];
  const float* hyp   = (const float*)d_in[2];
  const float* hmask = (const float*)d_in[3];
  float* out = (float*)d_out;

  char* ws = (char*)d_ws;
  unsigned short* simH = (unsigned short*)(ws);                // fp16, 32 MB
  unsigned short* simT = (unsigned short*)(ws + 33554432);     // fp16, 32 MB (2nd half of sim reservation)
  unsigned* rowMaxU = (unsigned*)(ws + 67108864);
  unsigned* colMaxU = (unsigned*)(ws + 67108864 + 2 * 65536);
  int* pIdx = (int*)(ws + 67108864 + 4 * 65536);
  int* hIdx = (int*)(ws + 67108864 + 5 * 65536);
  int* pCnt = (int*)(ws + 67108864 + 6 * 65536);
  int* hCnt = (int*)(ws + 67108864 + 6 * 65536 + 256);
  int* pPad = (int*)(ws + 67108864 + 6 * 65536 + 512);
  int* hPad = (int*)(ws + 67108864 + 6 * 65536 + 768);
  const size_t base2 = 67108864 + 4 * 65536 + 1048576;   // 68419584 (layout-stable)
  char* premD1 = (char*)(ws + base2);
  char* premD0 = (char*)(ws + base2 + 8388608);
  char* hypD1  = (char*)(ws + base2 + 16777216);
  char* hypD0  = (char*)(ws + base2 + 25165824);
  unsigned short* PremT = (unsigned short*)(ws + base2 + 33554432);
  unsigned short* HypT  = (unsigned short*)(ws + base2 + 50331648);
  const size_t need = base2 + 100663296;         // 169,082,880 (same as prior rounds)
  if (ws_size < need) return;

  scan_kernel<<<dim3(16, 2), 256, 0, stream>>>(pmask, hmask, pIdx, hIdx,
                                               pCnt, hCnt, pPad, hPad,
                                               rowMaxU, colMaxU);
  zero_out_kernel<<<dim3(8192), 256, 0, stream>>>(pmask, hmask, out);
  cvt_gather_kernel<<<dim3(8, 16, 32), 256, 0, stream>>>(
      prem, hyp, pIdx, hIdx, pCnt, hCnt, pPad, hPad,
      premD1, premD0, hypD1, hypD0, PremT, HypT);
  sim_gemm_v6_kernel<<<dim3(16, 8, NB), 256, 0, stream>>>(
      premD1, premD0, hypD1, hypD0, pCnt, hCnt, pPad, hPad,
      simH, simT, rowMaxU, colMaxU);
  av6_kernel<<<dim3(4, 16, 32), 256, 0, stream>>>(
      simH, simT, HypT, PremT, rowMaxU, colMaxU,
      pIdx, hIdx, pCnt, hCnt, pPad, hPad, out);
}

// Round 19
// 203.315 us; speedup vs baseline: 1.0824x; 1.0083x over previous
//
#include <hip/hip_runtime.h>
#include <hip/hip_fp16.h>
#include <math.h>

#define NB   16
#define SLA  1024
#define SLB  1024
#define HH   512

typedef __attribute__((ext_vector_type(4))) float  f32x4;
typedef __attribute__((ext_vector_type(8))) short  s16x8;
typedef __attribute__((ext_vector_type(4))) int    i32x4;

#define QS    (6.5f / 127.f)
#define QINVS (127.f / 6.5f)

__device__ __forceinline__ unsigned short f2bf(float x){
  unsigned u = __float_as_uint(x);
  u += 0x7fffu + ((u >> 16) & 1u);
  return (unsigned short)(u >> 16);
}
__device__ __forceinline__ float bf2f(unsigned short h){
  return __uint_as_float(((unsigned)h) << 16);
}
__device__ __forceinline__ float h2f(unsigned short h){
  return __half2float(__ushort_as_half(h));
}
// order-preserving float->uint key (monotone); atomicMax-able
__device__ __forceinline__ unsigned fkey(float f){
  unsigned u = __float_as_uint(f);
  return ((int)u < 0) ? ~u : (u | 0x80000000u);
}
__device__ __forceinline__ float funkey(unsigned k){
  return __uint_as_float((k & 0x80000000u) ? (k & 0x7fffffffu) : ~k);
}

// async global->LDS, 16B per lane. LDS dest must be wave-uniform base + lane*16.
__device__ __forceinline__ void gl2lds16(const void* g, void* l){
  __builtin_amdgcn_global_load_lds(
      (__attribute__((address_space(1))) unsigned int*)(unsigned long long)(size_t)g,
      (__attribute__((address_space(3))) unsigned int*)(unsigned int)(size_t)l,
      16, 0, 0);
}

// ---------------------------------------------------------------------------
// scan: per (batch, mask) compacted index list + counts; also zeroes the
// max-key accumulators for this (b, which).
// ---------------------------------------------------------------------------
__global__ __launch_bounds__(256) void scan_kernel(
    const float* __restrict__ pmask, const float* __restrict__ hmask,
    int* __restrict__ pIdx, int* __restrict__ hIdx,
    int* __restrict__ pCnt, int* __restrict__ hCnt,
    int* __restrict__ pPad, int* __restrict__ hPad,
    unsigned* __restrict__ rowMaxU, unsigned* __restrict__ colMaxU)
{
  __shared__ int ps[256];
  const int b     = blockIdx.x;
  const int which = blockIdx.y;
  const int t     = threadIdx.x;
  const float* m = (which ? hmask : pmask) + b * 1024;
  int* idx = (which ? hIdx : pIdx) + b * 1024;
  int* cnt = which ? hCnt : pCnt;
  int* pad = which ? hPad : pPad;

  // zero accumulators (independent of scan)
  #pragma unroll
  for (int v = 0; v < 4; ++v){
    int g = b * 1024 + t + v * 256;
    if (which == 0){
      rowMaxU[g] = 0u;
    } else {
      colMaxU[g] = 0u;
    }
  }

  int f[4], s = 0;
  #pragma unroll
  for (int e = 0; e < 4; ++e){
    f[e] = m[t * 4 + e] > 0.5f ? 1 : 0;
    s += f[e];
  }
  ps[t] = s;
  __syncthreads();
  for (int off = 1; off < 256; off <<= 1){
    int v = (t >= off) ? ps[t - off] : 0;
    __syncthreads();
    ps[t] += v;
    __syncthreads();
  }
  int pos = ps[t] - s;
  #pragma unroll
  for (int e = 0; e < 4; ++e){
    if (f[e]) idx[pos++] = t * 4 + e;
  }
  if (t == 0){
    int total = ps[255];
    cnt[b] = total;
    pad[b] = (total + 127) & ~127;
  }
}

// ---------------------------------------------------------------------------
// zero_out: zero the masked-out output rows (harness poisons d_out)
// ---------------------------------------------------------------------------
__global__ __launch_bounds__(256) void zero_out_kernel(
    const float* __restrict__ pmask, const float* __restrict__ hmask,
    float* __restrict__ out)
{
  const int r = blockIdx.x * 4 + (threadIdx.x >> 6);   // 0..32767
  const int side = r >> 14;
  const int b    = (r >> 10) & 15;
  const int row  = r & 1023;
  const float mv = (side ? hmask : pmask)[b * 1024 + row];
  if (mv > 0.5f) return;
  float4 z = {0.f, 0.f, 0.f, 0.f};
  float* p = out + (size_t)side * NB * SLA * HH
                 + ((size_t)b * 1024 + row) * 512 + (threadIdx.x & 63) * 8;
  *(float4*)p = z;
  *(float4*)(p + 4) = z;
}

// ---------------------------------------------------------------------------
// cvt_gather: gather masked-in rows -> i8 digit planes (compact) + bf16
// transposed XT [b][512][1024] (zeros in pad fringe). blockIdx.z = b+16*tensor
// ---------------------------------------------------------------------------
__global__ __launch_bounds__(256) void cvt_gather_kernel(
    const float* __restrict__ prem, const float* __restrict__ hyp,
    const int* __restrict__ pIdx, const int* __restrict__ hIdx,
    const int* __restrict__ pCnt, const int* __restrict__ hCnt,
    const int* __restrict__ pPad, const int* __restrict__ hPad,
    char* __restrict__ premD1, char* __restrict__ premD0,
    char* __restrict__ hypD1,  char* __restrict__ hypD0,
    unsigned short* __restrict__ PremT, unsigned short* __restrict__ HypT)
{
  __shared__ unsigned short tv[64][72];
  __shared__ int sIdx[64];

  const int tensor = blockIdx.z >> 4;
  const int b  = blockIdx.z & 15;
  const int l0 = blockIdx.y * 64;
  const int h0 = blockIdx.x * 64;
  const int t  = threadIdx.x;

  const int cnt = tensor ? hCnt[b] : pCnt[b];
  const int pad = tensor ? hPad[b] : pPad[b];
  if (l0 >= pad) return;

  const float* X = tensor ? hyp : prem;
  const int* idx = (tensor ? hIdx : pIdx) + b * 1024;
  char* D1 = tensor ? hypD1 : premD1;
  char* D0 = tensor ? hypD0 : premD0;
  unsigned short* XT = tensor ? HypT : PremT;

  if (t < 64){
    int jc = l0 + t;
    sIdx[t] = (jc < cnt) ? idx[jc] : -1;
  }
  __syncthreads();

  #pragma unroll
  for (int it = 0; it < 4; ++it){
    int r = (t >> 4) + it * 16;
    int c = (t & 15) * 4;
    int orig = sIdx[r];
    float4 x = {0.f, 0.f, 0.f, 0.f};
    if (orig >= 0)
      x = *(const float4*)(X + ((size_t)b * 1024 + orig) * HH + h0 + c);
    float xv[4] = {x.x, x.y, x.z, x.w};
    char d1v[4], d0v[4];
    #pragma unroll
    for (int e = 0; e < 4; ++e){
      float xs = xv[e] * QINVS;
      float x1 = rintf(xs);
      x1 = fminf(127.f, fmaxf(-127.f, x1));
      float x0 = rintf((xs - x1) * 256.f);
      x0 = fminf(127.f, fmaxf(-128.f, x0));
      d1v[e] = (char)(int)x1;
      d0v[e] = (char)(int)x0;
      tv[c + e][r] = f2bf(xv[e]);
    }
    size_t go = ((size_t)b * 1024 + l0 + r) * HH + h0 + c;
    *(char4*)(D1 + go) = make_char4(d1v[0], d1v[1], d1v[2], d1v[3]);
    *(char4*)(D0 + go) = make_char4(d0v[0], d0v[1], d0v[2], d0v[3]);
  }
  __syncthreads();
  const int w   = t >> 2;
  const int seg = (t & 3) * 16;
  const uint4* src = (const uint4*)&tv[w][seg];
  uint4* dst = (uint4*)(XT + ((size_t)b * HH + h0 + w) * 1024 + l0 + seg);
  dst[0] = src[0];
  dst[1] = src[1];
}

// ---------------------------------------------------------------------------
// sim_v7: compacted i8 GEMM -> sim fp16 AND simT fp16. Tile 64(M)x64(N),
// BK=64, 4 waves of 32x32 (av6's occupancy lever applied: acc halved to
// 32 VGPR, LDS 16KB staging / 9KB transpose union, grid (16,16,16) ->
// ~1024 live blocks = 4 blocks/CU vs v6's 2).
// Fused epilogue: masked row/col max -> atomicMax on uint keys.
// ---------------------------------------------------------------------------
__global__ __launch_bounds__(256, 4) void sim_gemm_v7_kernel(
    const char* __restrict__ premD1, const char* __restrict__ premD0,
    const char* __restrict__ hypD1,  const char* __restrict__ hypD0,
    const int* __restrict__ pCnt, const int* __restrict__ hCnt,
    const int* __restrict__ pPad, const int* __restrict__ hPad,
    unsigned short* __restrict__ simH, unsigned short* __restrict__ simT,
    unsigned* __restrict__ rowMaxU, unsigned* __restrict__ colMaxU)
{
  union __align__(16) Smem {
    struct {
      char A1[64 * 64];
      char A0[64 * 64];
      char B1[64 * 64];
      char B0[64 * 64];
    } g;                             // 16384 B (GEMM staging)
    unsigned short tp[64][72];       // 9216 B (epilogue transpose, +8 pad)
  };
  __shared__ Smem su;
#define sA1 (su.g.A1)
#define sA0 (su.g.A0)
#define sB1 (su.g.B1)
#define sB0 (su.g.B0)

  const int b  = blockIdx.z;
  const int i0 = blockIdx.y * 64;
  const int j0 = blockIdx.x * 64;
  const int t  = threadIdx.x;

  const int pc = pCnt[b], hc = hCnt[b];
  if (i0 >= pPad[b] || j0 >= hPad[b]) return;

  const char* A1 = premD1 + ((size_t)b * 1024 + i0) * HH;
  const char* A0 = premD0 + ((size_t)b * 1024 + i0) * HH;
  const char* B1 = hypD1  + ((size_t)b * 1024 + j0) * HH;
  const char* B0 = hypD0  + ((size_t)b * 1024 + j0) * HH;

  const int sr = t >> 2;                      // 0..63 staging row
  const int gc = ((t & 3) ^ (sr & 3)) * 16;   // swizzled 16B slot (global src)
  const int lco = (t & 3) * 16;               // linear LDS slot

  const int lane = t & 63;
  const int wr = (t >> 7) & 1;                // wave row (2x2 wave grid)
  const int wc = (t >> 6) & 1;                // wave col
  const int q  = lane >> 4;
  const int ln = lane & 15;
  const int fo = (q ^ (ln & 3)) * 16;         // frag read slot (matches gc)

  i32x4 acc1[2][2], accc[2][2];
  #pragma unroll
  for (int mt = 0; mt < 2; ++mt)
    #pragma unroll
    for (int nt = 0; nt < 2; ++nt){
      acc1[mt][nt] = (i32x4){0, 0, 0, 0};
      accc[mt][nt] = (i32x4){0, 0, 0, 0};
    }

  for (int k0 = 0; k0 < HH; k0 += 64){
    __syncthreads();
    {
      const size_t go = (size_t)sr * HH + k0 + gc;
      gl2lds16(A1 + go, &sA1[sr * 64 + lco]);
      gl2lds16(A0 + go, &sA0[sr * 64 + lco]);
      gl2lds16(B1 + go, &sB1[sr * 64 + lco]);
      gl2lds16(B0 + go, &sB0[sr * 64 + lco]);
    }
    __syncthreads();

    i32x4 af[2], bf1[2], bf0[2];
    #pragma unroll
    for (int mt = 0; mt < 2; ++mt)
      af[mt] = *(const i32x4*)&sA1[(wr * 32 + mt * 16 + ln) * 64 + fo];
    #pragma unroll
    for (int nt = 0; nt < 2; ++nt)
      bf1[nt] = *(const i32x4*)&sB1[(wc * 32 + nt * 16 + ln) * 64 + fo];
    #pragma unroll
    for (int mt = 0; mt < 2; ++mt)
      #pragma unroll
      for (int nt = 0; nt < 2; ++nt)
        acc1[mt][nt] = __builtin_amdgcn_mfma_i32_16x16x64_i8(af[mt], bf1[nt], acc1[mt][nt], 0, 0, 0);
    #pragma unroll
    for (int nt = 0; nt < 2; ++nt)
      bf0[nt] = *(const i32x4*)&sB0[(wc * 32 + nt * 16 + ln) * 64 + fo];
    #pragma unroll
    for (int mt = 0; mt < 2; ++mt)
      #pragma unroll
      for (int nt = 0; nt < 2; ++nt)
        accc[mt][nt] = __builtin_amdgcn_mfma_i32_16x16x64_i8(af[mt], bf0[nt], accc[mt][nt], 0, 0, 0);
    #pragma unroll
    for (int mt = 0; mt < 2; ++mt)
      af[mt] = *(const i32x4*)&sA0[(wr * 32 + mt * 16 + ln) * 64 + fo];
    #pragma unroll
    for (int mt = 0; mt < 2; ++mt)
      #pragma unroll
      for (int nt = 0; nt < 2; ++nt)
        accc[mt][nt] = __builtin_amdgcn_mfma_i32_16x16x64_i8(af[mt], bf1[nt], accc[mt][nt], 0, 0, 0);
  }

  const float S2 = QS * QS;
  unsigned short* simb = simH + ((size_t)b * SLA + i0) * SLB + j0;

  float rmx[8];
  #pragma unroll
  for (int e = 0; e < 8; ++e) rmx[e] = -1e30f;
  float cmx[2];
  cmx[0] = -1e30f; cmx[1] = -1e30f;

  __syncthreads();   // staging LDS dead; all waves past final frag reads -> tp reuse

  #pragma unroll
  for (int mt = 0; mt < 2; ++mt){
    #pragma unroll
    for (int nt = 0; nt < 2; ++nt){
      int col = wc * 32 + nt * 16 + ln;
      bool colv = (j0 + col) < hc;
      unsigned short hv[4];
      #pragma unroll
      for (int rr = 0; rr < 4; ++rr){
        int row = wr * 32 + mt * 16 + q * 4 + rr;
        float f = S2 * ((float)acc1[mt][nt][rr] + (float)accc[mt][nt][rr] * 0.00390625f);
        unsigned short hb = __half_as_ushort(__float2half(f));
        simb[(size_t)row * SLB + col] = hb;
        hv[rr] = hb;
        rmx[mt * 4 + rr] = fmaxf(rmx[mt * 4 + rr], colv ? f : -1e30f);
        cmx[nt] = fmaxf(cmx[nt], (i0 + row) < pc ? f : -1e30f);
      }
      uint2 w;
      w.x = (unsigned)hv[0] | ((unsigned)hv[1] << 16);
      w.y = (unsigned)hv[2] | ((unsigned)hv[3] << 16);
      *(uint2*)&su.tp[col][wr * 32 + mt * 16 + q * 4] = w;
    }
  }
  __syncthreads();
  {
    const int jr  = t >> 2;              // 0..63 simT row (j local)
    const int seg = (t & 3) * 16;        // i-local segment
    const uint4* src = (const uint4*)&su.tp[jr][seg];
    uint4* dst = (uint4*)(simT + ((size_t)b * SLB + j0 + jr) * SLA + i0 + seg);
    dst[0] = src[0];
    dst[1] = src[1];
  }

  #pragma unroll
  for (int e = 0; e < 8; ++e){
    float v = rmx[e];
    v = fmaxf(v, __shfl_xor(v, 1));
    v = fmaxf(v, __shfl_xor(v, 2));
    v = fmaxf(v, __shfl_xor(v, 4));
    v = fmaxf(v, __shfl_xor(v, 8));
    if (ln == 0){
      int row = wr * 32 + (e >> 2) * 16 + q * 4 + (e & 3);
      if (i0 + row < pc)
        atomicMax(rowMaxU + b * 1024 + i0 + row, fkey(v));
    }
  }
  #pragma unroll
  for (int nt = 0; nt < 2; ++nt){
    float v = cmx[nt];
    v = fmaxf(v, __shfl_xor(v, 16));
    v = fmaxf(v, __shfl_xor(v, 32));
    if (q == 0){
      int col = wc * 32 + nt * 16 + ln;
      if (j0 + col < hc)
        atomicMax(colMaxU + b * 1024 + j0 + col, fkey(v));
    }
  }
#undef sA1
#undef sA0
#undef sB1
#undef sB0
}

// ---------------------------------------------------------------------------
// av6: av3's proven 2-barrier structure, M-tile halved 128->64 for occupancy.
// MEASURED (R18): 43.3us vs av3's 53 (occ 17->22%, MfmaUtil 8.6, VALU 29,
// hbm 2.28 TB/s). Perf tracks waves/CU; manual pipelining regressed twice
// (Common-mistake #5). 4 waves at 32x64, LDS 25KB, ~4 blocks/CU.
// ---------------------------------------------------------------------------
__global__ __launch_bounds__(256, 4) void av6_kernel(
    const unsigned short* __restrict__ simH,
    const unsigned short* __restrict__ simT,
    const unsigned short* __restrict__ HypT, const unsigned short* __restrict__ PremT,
    const unsigned* __restrict__ rowMaxU, const unsigned* __restrict__ colMaxU,
    const int* __restrict__ pIdx, const int* __restrict__ hIdx,
    const int* __restrict__ pCnt, const int* __restrict__ hCnt,
    const int* __restrict__ pPad, const int* __restrict__ hPad,
    float* __restrict__ out)
{
  __shared__ unsigned short sA[64 * 64];    // 8 KB
  __shared__ unsigned short sB[128 * 64];   // 16 KB
  __shared__ float sScale[64];
  __shared__ int   sIdx[64];

  const int side = blockIdx.z >> 4;
  const int b    = blockIdx.z & 15;
  const int m0   = blockIdx.y * 64;
  const int n0   = blockIdx.x * 128;
  const int t    = threadIdx.x;

  const int cnt  = side ? hCnt[b] : pCnt[b];
  const int mpad = side ? hPad[b] : pPad[b];
  const int kpad = side ? pPad[b] : hPad[b];
  const int kcnt = side ? pCnt[b] : hCnt[b];
  if (m0 >= mpad) return;

  const int* idx = (side ? hIdx : pIdx) + b * 1024;
  float* o = out + (size_t)side * NB * SLA * HH + (size_t)b * 1024 * 512;

  if (t < 64) sIdx[t] = idx[m0 + t];

  // B staging pattern (gl2lds): 128 rows x 64 k, 4 waves x 4 issues
  const int wv = t >> 6;
  const int L  = t & 63;
  const int lr = L >> 3;
  const int sw = L & 7;
  const int gkc = (sw ^ lr) * 8;

  // A staging pattern (exp path): 64 rows, 4 threads/row (16 elems each)
  const int ar  = t >> 2;          // 0..63 m-row
  const int akh = (t & 3) * 16;    // k quarter (elements)

  // frag pattern: wave tile 32(M) x 64(N)
  const int lane = t & 63;
  const int wr = (t >> 7) & 1;
  const int wc = (t >> 6) & 1;
  const int q  = lane >> 4;
  const int ln = lane & 15;
  const int fsw = ln & 7;

  const unsigned short* As = (side ? simT : simH) + (size_t)b * 1024 * 1024;
  const unsigned short* Bt = (side ? PremT : HypT) + (size_t)b * 512 * 1024;
  const unsigned short* Arow = As + (size_t)(m0 + ar) * 1024 + akh;

  // per-thread row max, direct from global
  const float rm = funkey((side ? colMaxU : rowMaxU)[b * 1024 + m0 + ar]);

  float rs = 0.f;

  f32x4 acc[2][4];
  #pragma unroll
  for (int mt = 0; mt < 2; ++mt)
    #pragma unroll
    for (int nt = 0; nt < 4; ++nt)
      acc[mt][nt] = (f32x4){0.f, 0.f, 0.f, 0.f};

  for (int k0 = 0; k0 < kpad; k0 += 64){
    __syncthreads();   // prior frag reads done (also covers sIdx first iter)
    // B stage (async, in flight during A exp work)
    #pragma unroll
    for (int s = 0; s < 4; ++s){
      int row = wv * 32 + s * 8 + lr;
      gl2lds16(Bt + (size_t)(n0 + row) * 1024 + k0 + gkc, &sB[row * 64 + sw * 8]);
    }
    // A: read sim fp16 row quarter, exp, accumulate row sum, ds_write swizzled
    {
      const unsigned short* sp = Arow + k0;
      const bool full = (k0 + 64 <= kcnt);   // block-uniform branch
      #pragma unroll
      for (int cc = 0; cc < 2; ++cc){
        uint4 u = *(const uint4*)(sp + cc * 8);
        unsigned uw[4] = {u.x, u.y, u.z, u.w};
        unsigned short pb[8];
        if (full){
          #pragma unroll
          for (int d = 0; d < 4; ++d){
            float v0 = h2f((unsigned short)(uw[d] & 0xffff));
            float v1 = h2f((unsigned short)(uw[d] >> 16));
            float p0 = __expf(v0 - rm);
            float p1 = __expf(v1 - rm);
            rs += p0 + p1;
            pb[d * 2]     = f2bf(p0);
            pb[d * 2 + 1] = f2bf(p1);
          }
        } else {
          int kb = k0 + akh + cc * 8;
          #pragma unroll
          for (int d = 0; d < 4; ++d){
            float v0 = h2f((unsigned short)(uw[d] & 0xffff));
            float v1 = h2f((unsigned short)(uw[d] >> 16));
            float p0 = (kb + d * 2 + 0) < kcnt ? __expf(v0 - rm) : 0.f;
            float p1 = (kb + d * 2 + 1) < kcnt ? __expf(v1 - rm) : 0.f;
            rs += p0 + p1;
            pb[d * 2]     = f2bf(p0);
            pb[d * 2 + 1] = f2bf(p1);
          }
        }
        uint4 w;
        w.x = (unsigned)pb[0] | ((unsigned)pb[1] << 16);
        w.y = (unsigned)pb[2] | ((unsigned)pb[3] << 16);
        w.z = (unsigned)pb[4] | ((unsigned)pb[5] << 16);
        w.w = (unsigned)pb[6] | ((unsigned)pb[7] << 16);
        int c   = (t & 3) * 2 + cc;          // 8-elem group index 0..7
        int pos = c ^ (ar & 7);              // matches read g ^ (row&7)
        *(uint4*)&sA[ar * 64 + pos * 8] = w;
      }
    }
    __syncthreads();

    #pragma unroll
    for (int h = 0; h < 2; ++h){
      s16x8 af[2], bfr[4];
      #pragma unroll
      for (int mt = 0; mt < 2; ++mt){
        int r = wr * 32 + mt * 16 + ln;
        af[mt] = *(const s16x8*)&sA[r * 64 + (((h << 2) + q) ^ fsw) * 8];
      }
      #pragma unroll
      for (int nt = 0; nt < 4; ++nt){
        int r = wc * 64 + nt * 16 + ln;
        bfr[nt] = *(const s16x8*)&sB[r * 64 + (((h << 2) + q) ^ fsw) * 8];
      }
      #pragma unroll
      for (int mt = 0; mt < 2; ++mt)
        #pragma unroll
        for (int nt = 0; nt < 4; ++nt)
          acc[mt][nt] = __builtin_amdgcn_mfma_f32_16x16x32_bf16(af[mt], bfr[nt], acc[mt][nt], 0, 0, 0);
    }
  }

  // combine the 4 k-quarters of row ar (threads t^1, t^2 share ar)
  rs += __shfl_xor(rs, 1);
  rs += __shfl_xor(rs, 2);
  __syncthreads();                  // sA dead; reuse barrier before sScale write
  if ((t & 3) == 0) sScale[ar] = 1.f / rs;
  __syncthreads();

  #pragma unroll
  for (int mt = 0; mt < 2; ++mt)
    #pragma unroll
    for (int nt = 0; nt < 4; ++nt){
      int col = n0 + wc * 64 + nt * 16 + ln;
      #pragma unroll
      for (int rr = 0; rr < 4; ++rr){
        int rowL = wr * 32 + mt * 16 + q * 4 + rr;
        if (m0 + rowL < cnt)
          o[(size_t)sIdx[rowL] * 512 + col] = acc[mt][nt][rr] * sScale[rowL];
      }
    }
}

// ---------------------------------------------------------------------------
extern "C" void kernel_launch(void* const* d_in, const int* in_sizes, int n_in,
                              void* d_out, int out_size, void* d_ws, size_t ws_size,
                              hipStream_t stream)
{
  const float* prem  = (const float*)d_in[0];
  const float* pmask = (const float*)d_in[1];
  const float* hyp   = (const float*)d_in[2];
  const float* hmask = (const float*)d_in[3];
  float* out = (float*)d_out;

  char* ws = (char*)d_ws;
  unsigned short* simH = (unsigned short*)(ws);                // fp16, 32 MB
  unsigned short* simT = (unsigned short*)(ws + 33554432);     // fp16, 32 MB (2nd half of sim reservation)
  unsigned* rowMaxU = (unsigned*)(ws + 67108864);
  unsigned* colMaxU = (unsigned*)(ws + 67108864 + 2 * 65536);
  int* pIdx = (int*)(ws + 67108864 + 4 * 65536);
  int* hIdx = (int*)(ws + 67108864 + 5 * 65536);
  int* pCnt = (int*)(ws + 67108864 + 6 * 65536);
  int* hCnt = (int*)(ws + 67108864 + 6 * 65536 + 256);
  int* pPad = (int*)(ws + 67108864 + 6 * 65536 + 512);
  int* hPad = (int*)(ws + 67108864 + 6 * 65536 + 768);
  const size_t base2 = 67108864 + 4 * 65536 + 1048576;   // 68419584 (layout-stable)
  char* premD1 = (char*)(ws + base2);
  char* premD0 = (char*)(ws + base2 + 8388608);
  char* hypD1  = (char*)(ws + base2 + 16777216);
  char* hypD0  = (char*)(ws + base2 + 25165824);
  unsigned short* PremT = (unsigned short*)(ws + base2 + 33554432);
  unsigned short* HypT  = (unsigned short*)(ws + base2 + 50331648);
  const size_t need = base2 + 100663296;         // 169,082,880 (same as prior rounds)
  if (ws_size < need) return;

  scan_kernel<<<dim3(16, 2), 256, 0, stream>>>(pmask, hmask, pIdx, hIdx,
                                               pCnt, hCnt, pPad, hPad,
                                               rowMaxU, colMaxU);
  zero_out_kernel<<<dim3(8192), 256, 0, stream>>>(pmask, hmask, out);
  cvt_gather_kernel<<<dim3(8, 16, 32), 256, 0, stream>>>(
      prem, hyp, pIdx, hIdx, pCnt, hCnt, pPad, hPad,
      premD1, premD0, hypD1, hypD0, PremT, HypT);
  sim_gemm_v7_kernel<<<dim3(16, 16, NB), 256, 0, stream>>>(
      premD1, premD0, hypD1, hypD0, pCnt, hCnt, pPad, hPad,
      simH, simT, rowMaxU, colMaxU);
  av6_kernel<<<dim3(4, 16, 32), 256, 0, stream>>>(
      simH, simT, HypT, PremT, rowMaxU, colMaxU,
      pIdx, hIdx, pCnt, hCnt, pPad, hPad, out);
}